// Round 20
// baseline (107.078 us; speedup 1.0000x reference)
//
#include <hip/hip_runtime.h>
#include <string.h>

// Exact k-th order statistic + mask, fp32, n = 64*1024*1024.
// Fused single-full-pass, pure-float hot loop (no map_bits outside rare branch):
//   k1_fused : read x (float4), NT-write PROVISIONAL mask (v >= f_hi);
//              per-uint4 below-count (v < f_lo) -> ONE private-slot LDS atomic;
//              window elems (2% of waves): map_bits + 1-ulp global hist +
//              per-block compaction
//   anchor_select : below = st[2]; exact verify + window select -> thr
//   fixup : scatter 1.0f for the ~23K window elems >= thr (gated flag==0)
//   fb_all : ONE gated kernel = complete 3-pass radix select (never taken);
//            gated full re-mask after it.
//
// state: [2]=below [3]=flag [8]=thr mapped-u [9]=thr float bits
// ws ints: ST(32)|HWIN(16384)|CNTB(2048) <- zeroed | CAND(2048 x 256 x uint2)

#define N_STATE  32
#define HWIN_OFF 32
#define NWIN     16384
#define CNTB_OFF (HWIN_OFF + NWIN)
#define NBLK     2048
#define FIXED_Z  (CNTB_OFF + NBLK)            // ~74 KB zeroed per call
#define CAND_OFF FIXED_Z
#define BSEG     256u

#define FB_WS_INTS (16 + 4096 + 4096 + 256)

typedef float vfloat4 __attribute__((ext_vector_type(4)));

__device__ __forceinline__ unsigned map_bits(unsigned raw) {
    return (raw & 0x80000000u) ? ~raw : (raw | 0x80000000u);
}

// ---------------- workspace zeroing ----------------
__global__ void __launch_bounds__(256)
zero_ws(uint4* __restrict__ p, int n16)
{
    int i = blockIdx.x * 256 + threadIdx.x;
    int s = gridDim.x * 256;
    uint4 z = make_uint4(0u, 0u, 0u, 0u);
    for (; i < n16; i += s) p[i] = z;
}

// ---------------- k1: fused mask + below-count + window compaction ---------
__global__ void __launch_bounds__(256)
k1_fused(const float4* __restrict__ x, int n4, vfloat4* __restrict__ out,
         unsigned* __restrict__ st, unsigned* __restrict__ hwin,
         uint2* __restrict__ cand, unsigned* __restrict__ cntb,
         unsigned u0, float f_lo, float f_hi)
{
    __shared__ unsigned c[256];
    __shared__ unsigned bcnt;
    c[threadIdx.x] = 0u;
    if (threadIdx.x == 0) bcnt = 0u;
    __syncthreads();

    uint2* seg = cand + (size_t)blockIdx.x * BSEG;
    int idx = blockIdx.x * 256 + threadIdx.x;
    int S = gridDim.x * 256;
    for (int i = idx; i < n4; i += S) {
        float4 v = x[i];
        vfloat4 o;
        bool ba = v.x < f_lo, bb = v.y < f_lo, bc = v.z < f_lo, bd = v.w < f_lo;
        bool ga = v.x >= f_hi, gb = v.y >= f_hi, gc = v.z >= f_hi, gd = v.w >= f_hi;
        o[0] = ga ? 1.0f : 0.0f;
        o[1] = gb ? 1.0f : 0.0f;
        o[2] = gc ? 1.0f : 0.0f;
        o[3] = gd ? 1.0f : 0.0f;
        unsigned cnt4 = (ba ? 1u : 0u) + (bb ? 1u : 0u)
                      + (bc ? 1u : 0u) + (bd ? 1u : 0u);
        atomicAdd(&c[threadIdx.x], cnt4);      // private slot: no contention
        bool wa = !(ba | ga), wb = !(bb | gb);
        bool wc = !(bc | gc), wd = !(bd | gd);
        if (wa | wb | wc | wd) {               // wave-skipped ~98% of the time
            unsigned gi = (unsigned)i * 4u;
            if (wa) { unsigned u = map_bits(__float_as_uint(v.x));
                      if ((u - u0) < (unsigned)NWIN) {
                          atomicAdd(&hwin[u - u0], 1u);
                          unsigned sl = atomicAdd(&bcnt, 1u);
                          if (sl < BSEG) seg[sl] = make_uint2(u, gi + 0u); } }
            if (wb) { unsigned u = map_bits(__float_as_uint(v.y));
                      if ((u - u0) < (unsigned)NWIN) {
                          atomicAdd(&hwin[u - u0], 1u);
                          unsigned sl = atomicAdd(&bcnt, 1u);
                          if (sl < BSEG) seg[sl] = make_uint2(u, gi + 1u); } }
            if (wc) { unsigned u = map_bits(__float_as_uint(v.z));
                      if ((u - u0) < (unsigned)NWIN) {
                          atomicAdd(&hwin[u - u0], 1u);
                          unsigned sl = atomicAdd(&bcnt, 1u);
                          if (sl < BSEG) seg[sl] = make_uint2(u, gi + 2u); } }
            if (wd) { unsigned u = map_bits(__float_as_uint(v.w));
                      if ((u - u0) < (unsigned)NWIN) {
                          atomicAdd(&hwin[u - u0], 1u);
                          unsigned sl = atomicAdd(&bcnt, 1u);
                          if (sl < BSEG) seg[sl] = make_uint2(u, gi + 3u); } }
        }
        __builtin_nontemporal_store(o, &out[i]);
    }
    __syncthreads();
    for (int off = 128; off > 0; off >>= 1) {
        if (threadIdx.x < (unsigned)off) c[threadIdx.x] += c[threadIdx.x + off];
        __syncthreads();
    }
    if (threadIdx.x == 0) {
        atomicAdd(&st[2], c[0]);
        cntb[blockIdx.x] = bcnt;
    }
}

// ---------------- exact anchor + verification + window select ----------------
__global__ void __launch_bounds__(1024)
anchor_select(const unsigned* __restrict__ hwin, const unsigned* __restrict__ cntb,
              unsigned r, unsigned u0, unsigned* __restrict__ st)
{
    __shared__ unsigned s[1024];
    __shared__ unsigned sm[1024];
    __shared__ unsigned sh_rank, sh_flag, sh_max;
    int t = threadIdx.x;

    // phase 1: max of per-block counts
    unsigned mx = 0;
    for (int j = t; j < NBLK; j += 1024) {
        unsigned cc = cntb[j];
        mx = (cc > mx) ? cc : mx;
    }
    sm[t] = mx;
    __syncthreads();
    for (int off = 512; off > 0; off >>= 1) {
        if (t < off) sm[t] = (sm[t + off] > sm[t]) ? sm[t + off] : sm[t];
        __syncthreads();
    }
    if (t == 0) sh_max = sm[0];
    __syncthreads();

    // phase 2: prefix over hwin (16 bins/thread)
    unsigned loc[16];
    unsigned mySum = 0;
    int base = t * 16;
    #pragma unroll
    for (int j = 0; j < 16; ++j) { loc[j] = hwin[base + j]; mySum += loc[j]; }
    s[t] = mySum;
    __syncthreads();
    for (int off = 1; off < 1024; off <<= 1) {
        unsigned v = (t >= off) ? s[t - off] : 0u;
        __syncthreads();
        s[t] += v;
        __syncthreads();
    }
    unsigned Nwin = s[1023];
    if (t == 0) {
        unsigned long long below = st[2];
        unsigned flag = 0;
        if (sh_max > BSEG) flag = 1;          // block segment overflow
        if (!((below <= (unsigned long long)r) &&
              ((unsigned long long)r < below + (unsigned long long)Nwin))) flag = 1;
        st[3] = flag;
        sh_flag = flag;
        sh_rank = (unsigned)((unsigned long long)r - below);
    }
    __syncthreads();
    if (sh_flag != 0u) return;
    unsigned rank = sh_rank;
    unsigned incl = s[t], excl = incl - mySum;
    if (rank >= excl && rank < incl) {
        unsigned run = excl;
        #pragma unroll
        for (int j = 0; j < 16; ++j) {
            if (rank < run + loc[j]) {
                unsigned u = u0 + (unsigned)(base + j);
                st[8] = u;                                            // mapped thr
                st[9] = (u & 0x80000000u) ? (u & 0x7FFFFFFFu) : ~u;   // float bits
                break;
            }
            run += loc[j];
        }
    }
}

// ---------------- fixup (gated flag==0) ----------------
__global__ void __launch_bounds__(64)
fixup(const uint2* __restrict__ cand, const unsigned* __restrict__ cntb,
      const unsigned* __restrict__ st, float* __restrict__ out)
{
    if (st[3] != 0u) return;
    unsigned thr = st[8];
    unsigned b = blockIdx.x;
    unsigned m = cntb[b]; if (m > BSEG) m = BSEG;
    const uint2* seg = cand + (size_t)b * BSEG;
    for (unsigned j = threadIdx.x; j < m; j += 64u) {
        uint2 cv = seg[j];
        if (cv.x >= thr) out[cv.y] = 1.0f;
    }
}

// ---------------- in-block select helper (1024 threads) ----------------
__device__ __forceinline__ void block_select1024(
    const unsigned* __restrict__ h, int nbins, unsigned rank,
    unsigned* s, unsigned* sh_bin, unsigned* sh_rank)
{
    int t = threadIdx.x;
    int per = (nbins + 1023) >> 10;
    int base = t * per;
    unsigned mySum = 0;
    for (int j = 0; j < per; ++j) {
        int b = base + j;
        if (b < nbins) mySum += h[b];
    }
    s[t] = mySum;
    __syncthreads();
    for (int off = 1; off < 1024; off <<= 1) {
        unsigned v = (t >= off) ? s[t - off] : 0u;
        __syncthreads();
        s[t] += v;
        __syncthreads();
    }
    unsigned incl = s[t], excl = incl - mySum;
    if (rank >= excl && rank < incl) {
        unsigned run = excl;
        for (int j = 0; j < per; ++j) {
            int b = base + j;
            unsigned c = (b < nbins) ? h[b] : 0u;
            if (rank < run + c) { *sh_bin = (unsigned)b; *sh_rank = rank - run; break; }
            run += c;
        }
    }
    __syncthreads();
}

// ---------------- fb_all: complete 3-pass radix select, ONE gated kernel ----
__global__ void __launch_bounds__(1024)
fb_all(const uint4* __restrict__ x, int n4, unsigned r, unsigned* __restrict__ st)
{
    if (st[3] == 0u) return;
    __shared__ unsigned h[4096];
    __shared__ unsigned s[1024];
    __shared__ unsigned sh_bin, sh_rank;
    int t = threadIdx.x;

    // pass 1: top-12 bits
    for (int i = t; i < 4096; i += 1024) h[i] = 0u;
    __syncthreads();
    for (int i = t; i < n4; i += 1024) {
        uint4 v = x[i];
        atomicAdd(&h[map_bits(v.x) >> 20], 1u);
        atomicAdd(&h[map_bits(v.y) >> 20], 1u);
        atomicAdd(&h[map_bits(v.z) >> 20], 1u);
        atomicAdd(&h[map_bits(v.w) >> 20], 1u);
    }
    __syncthreads();
    block_select1024(h, 4096, r, s, &sh_bin, &sh_rank);
    unsigned b1 = sh_bin, r2 = sh_rank;
    __syncthreads();

    // pass 2: mid-12 bits within b1
    for (int i = t; i < 4096; i += 1024) h[i] = 0u;
    __syncthreads();
    for (int i = t; i < n4; i += 1024) {
        uint4 v = x[i];
        unsigned u;
        u = map_bits(v.x); if ((u >> 20) == b1) atomicAdd(&h[(u >> 8) & 4095u], 1u);
        u = map_bits(v.y); if ((u >> 20) == b1) atomicAdd(&h[(u >> 8) & 4095u], 1u);
        u = map_bits(v.z); if ((u >> 20) == b1) atomicAdd(&h[(u >> 8) & 4095u], 1u);
        u = map_bits(v.w); if ((u >> 20) == b1) atomicAdd(&h[(u >> 8) & 4095u], 1u);
    }
    __syncthreads();
    block_select1024(h, 4096, r2, s, &sh_bin, &sh_rank);
    unsigned b2 = sh_bin, r3 = sh_rank;
    __syncthreads();

    // pass 3: low-8 bits within (b1,b2)
    for (int i = t; i < 4096; i += 1024) h[i] = 0u;
    __syncthreads();
    unsigned pfx = (b1 << 12) | b2;
    for (int i = t; i < n4; i += 1024) {
        uint4 v = x[i];
        unsigned u;
        u = map_bits(v.x); if ((u >> 8) == pfx) atomicAdd(&h[u & 255u], 1u);
        u = map_bits(v.y); if ((u >> 8) == pfx) atomicAdd(&h[u & 255u], 1u);
        u = map_bits(v.z); if ((u >> 8) == pfx) atomicAdd(&h[u & 255u], 1u);
        u = map_bits(v.w); if ((u >> 8) == pfx) atomicAdd(&h[u & 255u], 1u);
    }
    __syncthreads();
    block_select1024(h, 256, r3, s, &sh_bin, &sh_rank);
    if (t == 0) {
        unsigned u = (b1 << 20) | (b2 << 8) | sh_bin;
        st[9] = (u & 0x80000000u) ? (u & 0x7FFFFFFFu) : ~u;   // inverse map
    }
}

// ---------------- full re-mask (fallback path only, flag-gated) ------------
__global__ void __launch_bounds__(256)
mask_kernel(const float4* __restrict__ x, float4* __restrict__ out, int n4,
            const unsigned* __restrict__ st, const unsigned* __restrict__ gate)
{
    if (gate && *gate == 0u) return;
    float thr = __uint_as_float(st[9]);
    int idx = blockIdx.x * blockDim.x + threadIdx.x;
    int stride = gridDim.x * blockDim.x;
    for (int i = idx; i < n4; i += stride) {
        float4 v = x[i];
        float4 o;
        o.x = (v.x >= thr) ? 1.0f : 0.0f;
        o.y = (v.y >= thr) ? 1.0f : 0.0f;
        o.z = (v.z >= thr) ? 1.0f : 0.0f;
        o.w = (v.w >= thr) ? 1.0f : 0.0f;
        out[i] = o;
    }
}

// ---------------- small-ws standalone fallback kernels ----------------
__global__ void __launch_bounds__(256)
hist_pass(const uint4* __restrict__ x, int n4, int shift, int nbins, int mode,
          const unsigned* __restrict__ state, unsigned* __restrict__ hist,
          const unsigned* __restrict__ gate)
{
    if (gate && *gate == 0u) return;
    __shared__ unsigned lh[4096];
    for (int i = threadIdx.x; i < nbins; i += blockDim.x) lh[i] = 0u;
    __syncthreads();

    unsigned tgt = 0; int mshift = 0;
    if (mode == 1)      { tgt = state[0];                      mshift = 20; }
    else if (mode == 2) { tgt = (state[0] << 12) | state[2];   mshift = 8;  }

    const unsigned binmask = (unsigned)(nbins - 1);
    int idx = blockIdx.x * blockDim.x + threadIdx.x;
    int stride = gridDim.x * blockDim.x;
    for (int i = idx; i < n4; i += stride) {
        uint4 v = x[i];
        unsigned u;
        u = map_bits(v.x); if (!mode || (u >> mshift) == tgt) atomicAdd(&lh[(u >> shift) & binmask], 1u);
        u = map_bits(v.y); if (!mode || (u >> mshift) == tgt) atomicAdd(&lh[(u >> shift) & binmask], 1u);
        u = map_bits(v.z); if (!mode || (u >> mshift) == tgt) atomicAdd(&lh[(u >> shift) & binmask], 1u);
        u = map_bits(v.w); if (!mode || (u >> mshift) == tgt) atomicAdd(&lh[(u >> shift) & binmask], 1u);
    }
    __syncthreads();
    for (int i = threadIdx.x; i < nbins; i += blockDim.x) {
        unsigned c = lh[i];
        if (c) atomicAdd(&hist[i], c);
    }
}

__global__ void __launch_bounds__(1024)
scan_select(const unsigned* __restrict__ hist, int nbins,
            const unsigned* __restrict__ rank_in, unsigned rank_imm,
            unsigned* __restrict__ bin_out, unsigned* __restrict__ rank_out,
            const unsigned* __restrict__ gate, int want_nonzero)
{
    if (gate) {
        unsigned g = *gate;
        if ((g != 0u) != (want_nonzero != 0)) return;
    }
    __shared__ unsigned s[1024];
    int t = threadIdx.x;
    unsigned rank = rank_in ? *rank_in : rank_imm;
    int per = (nbins + 1023) >> 10;
    int base = t * per;
    unsigned mySum = 0;
    for (int i = 0; i < per; ++i) {
        int b = base + i;
        if (b < nbins) mySum += hist[b];
    }
    s[t] = mySum;
    __syncthreads();
    for (int off = 1; off < 1024; off <<= 1) {
        unsigned v = (t >= off) ? s[t - off] : 0u;
        __syncthreads();
        s[t] += v;
        __syncthreads();
    }
    unsigned incl = s[t];
    unsigned excl = incl - mySum;
    if (rank >= excl && rank < incl) {
        unsigned run = excl;
        for (int i = 0; i < per; ++i) {
            int b = base + i;
            unsigned c = (b < nbins) ? hist[b] : 0u;
            if (rank < run + c) { *bin_out = (unsigned)b; *rank_out = rank - run; break; }
            run += c;
        }
    }
}

__global__ void finalize_thr_fb(unsigned* st, const unsigned* gate) {
    if (gate && *gate == 0u) return;
    unsigned u = (st[10] << 20) | (st[12] << 8) | st[14];
    st[9] = (u & 0x80000000u) ? (u & 0x7FFFFFFFu) : ~u;
}

// ---------------- host ----------------
static inline unsigned host_map(float f) {
    unsigned raw; memcpy(&raw, &f, 4);
    return (raw & 0x80000000u) ? ~raw : (raw | 0x80000000u);
}
static inline float host_unmap(unsigned u) {
    unsigned raw = (u & 0x80000000u) ? (u & 0x7FFFFFFFu) : ~u;
    float f; memcpy(&f, &raw, 4);
    return f;
}

extern "C" void kernel_launch(void* const* d_in, const int* in_sizes, int n_in,
                              void* d_out, int out_size, void* d_ws, size_t ws_size,
                              hipStream_t stream)
{
    const float* x = (const float*)d_in[0];
    float* out = (float*)d_out;
    long long n = (long long)in_sizes[0];
    long long k = (long long)((double)n * 0.9);   // matches Python int(n * RATIO)

    if (k <= 0) {
        hipMemsetAsync(d_out, 0, (size_t)out_size * sizeof(float), stream);
        return;
    }

    unsigned* ws = (unsigned*)d_ws;
    unsigned* st = ws;
    int n4 = (int)(n / 4);
    const uint4* x4 = (const uint4*)x;
    unsigned r = (unsigned)(n - k);               // ascending rank of threshold

    size_t need_fast = ((size_t)CAND_OFF + (size_t)NBLK * BSEG * 2) * 4;

    if (ws_size >= need_fast) {
        unsigned* hwin = ws + HWIN_OFF;
        unsigned* cntb = ws + CNTB_OFF;
        uint2*    cand = (uint2*)(ws + CAND_OFF);

        // Static window around the 0.1-quantile of N(0,1), u* = map(-1.2816):
        // window = 16384 ulp ~= +-4.7 sigma of the sample-quantile position.
        // f_lo/f_hi are the exact float values of the window bounds (map is a
        // monotone bijection), so hot-loop compares run in float directly.
        // Exactness NEVER depends on the window: flag-verified; fb_all
        // re-solves exactly and the gated re-mask rewrites the full output.
        unsigned ustar = host_map(-1.2816f);
        unsigned u0  = ustar - (unsigned)(NWIN / 2);
        unsigned hiw = u0 + (unsigned)NWIN;
        float f_lo = host_unmap(u0);
        float f_hi = host_unmap(hiw);

        zero_ws<<<64, 256, 0, stream>>>((uint4*)d_ws, (FIXED_Z + 3) / 4);
        k1_fused<<<NBLK, 256, 0, stream>>>((const float4*)x, n4, (vfloat4*)out,
                                           st, hwin, cand, cntb, u0, f_lo, f_hi);
        anchor_select<<<1, 1024, 0, stream>>>(hwin, cntb, r, u0, st);
        fixup<<<NBLK, 64, 0, stream>>>(cand, cntb, st, out);
        fb_all<<<1, 1024, 0, stream>>>(x4, n4, r, st);
        mask_kernel<<<1024, 256, 0, stream>>>((const float4*)x, (float4*)out, n4, st, &st[3]);
    } else {
        // small-ws standalone fallback: 3-pass radix + mask (ungated)
        unsigned* h1 = ws + 16;
        unsigned* h2 = ws + 16 + 4096;
        unsigned* h3 = ws + 16 + 8192;

        hipMemsetAsync(d_ws, 0, FB_WS_INTS * sizeof(unsigned), stream);

        hist_pass<<<2048, 256, 0, stream>>>(x4, n4, 20, 4096, 0, &ws[10], h1, nullptr);
        scan_select<<<1, 1024, 0, stream>>>(h1, 4096, nullptr, r, &ws[10], &ws[11], nullptr, 0);
        hist_pass<<<2048, 256, 0, stream>>>(x4, n4, 8, 4096, 1, &ws[10], h2, nullptr);
        scan_select<<<1, 1024, 0, stream>>>(h2, 4096, &ws[11], 0u, &ws[12], &ws[13], nullptr, 0);
        hist_pass<<<2048, 256, 0, stream>>>(x4, n4, 0, 256, 2, &ws[10], h3, nullptr);
        scan_select<<<1, 1024, 0, stream>>>(h3, 256, &ws[13], 0u, &ws[14], &ws[15], nullptr, 0);
        finalize_thr_fb<<<1, 1, 0, stream>>>(ws, nullptr);
        mask_kernel<<<2048, 256, 0, stream>>>((const float4*)x, (float4*)out, n4, ws, nullptr);
    }
}